// Round 10
// baseline (47.502 us; speedup 1.0000x reference)
//
#include <hip/hip_runtime.h>
#include <hip/hip_bf16.h>

#define N_ROWS 8192
#define DIM 128

typedef short v8s  __attribute__((ext_vector_type(8)));   // 8 bf16 (4 VGPRs) MFMA A/B frag
typedef float v16f __attribute__((ext_vector_type(16)));  // 32x32 MFMA C/D frag
typedef float v2f  __attribute__((ext_vector_type(2)));   // packed-f32 pair (v_pk_*)
typedef unsigned int u32;

constexpr int NS = 16;                // j-splits (blockIdx.y)
constexpr int CW = N_ROWS / NS;       // 512 j-rows per split
constexpr int NSLOT = NS;             // partial slots (one per j-split)
constexpr int TILE_J = 32;            // LDS-staged j-rows per tile
constexpr int NT = CW / TILE_J;       // 16 tiles per block
constexpr int TB = TILE_J * DIM * 2;  // 8 KB per buffer
constexpr int BI = 256;               // block i-width (8 waves x 32 cols)
constexpr int NRB = N_ROWS / 64;      // kreduce blocks (128)
constexpr float T2 = 0.0625f;         // THRESH^2: |pi-pj|<0.25 <=> d^2<0.0625
constexpr float C1 = 14.426950408889634f;  // 10*log2(e): exp(10*dot-10)=2^(C1*dot-C1)

// global->LDS async copy; size must be a literal (macro keeps it one).
#define GLDS(gptr, lptr, sz)                                                   \
  __builtin_amdgcn_global_load_lds(                                            \
      (const __attribute__((address_space(1))) u32*)(gptr),                    \
      (__attribute__((address_space(3))) u32*)(lptr), sz, 0, 0)

__device__ __forceinline__ unsigned short f2bf(float f) {
  __hip_bfloat16 h = __float2bfloat16(f);
  return __builtin_bit_cast(unsigned short, h);
}

// ---------------- kernel 1: L2-normalize rows, cast to bf16 ----------------
// Also re-initializes the kreduce ticket counter every call (stream order
// guarantees it lands before kreduce reads it; no state across replays).
__global__ __launch_bounds__(256) void knorm(const float* __restrict__ emb,
                                             unsigned short* __restrict__ ebf,
                                             int* __restrict__ cnt) {
  if (blockIdx.x == 0 && threadIdx.x == 0) cnt[0] = 0;
  const int row  = blockIdx.x * 4 + (threadIdx.x >> 6);  // one wave per row
  const int lane = threadIdx.x & 63;
  const float2 v = *reinterpret_cast<const float2*>(emb + (size_t)row * DIM + lane * 2);
  float ss = fmaf(v.x, v.x, v.y * v.y);
#pragma unroll
  for (int off = 32; off > 0; off >>= 1) ss += __shfl_xor(ss, off);
  const float rn = 1.0f / sqrtf(ss);
  const unsigned int packed =
      (unsigned int)f2bf(v.x * rn) | ((unsigned int)f2bf(v.y * rn) << 16);
  *reinterpret_cast<unsigned int*>(ebf + (size_t)row * DIM + lane * 2) = packed;
}

// ---------------- kernel 2: fused sim-GEMM + row stats, 32x32 MFMA ----------------
// R9 structure (8-wave blocks, persistent B-frags, one 16B GLDS/thread/tile,
// pre-swizzled source + XOR ds_read, packed-f32 epilogue) with HALF the
// barriers: 4 LDS buffers, {stage 2 tiles; compute 2 tiles; __syncthreads}
// per iteration -> convoy points per j-row halved vs R9.
// C/D layout (m74/m101): col = lane&31, row = (reg&3)+8*(reg>>2)+4*(lane>>5).
__global__ __launch_bounds__(512) void kmain(const unsigned short* __restrict__ ebf,
                                             const float* __restrict__ props,
                                             float* __restrict__ part) {
  const int tid  = threadIdx.x;
  const int lane = tid & 63;
  const int w    = tid >> 6;           // 0..7
  const int r31  = lane & 31;          // A-row / C-col index
  const int hi   = lane >> 5;          // 0..1
  const int i0   = blockIdx.x * BI;    // block i-range (256 cols)
  const int iw0  = i0 + w * 32;        // wave i-range
  const int jbase = blockIdx.y * CW;

  __shared__ __align__(1024) char sA[4 * TB + CW * 4];
  char* sprops = sA + 4 * TB;

  const int icol = iw0 + r31;          // this lane's output column

  // persistent B-frags: frag kk holds e[icol][kk*16 + hi*8 .. +8)
  v8s bfr[8];
#pragma unroll
  for (int kk = 0; kk < 8; ++kk)
    bfr[kk] = *reinterpret_cast<const v8s*>(ebf + (size_t)icol * DIM + kk * 16 + hi * 8);
  const float pc = props[icol];

  // stage props[jbase .. +512) into LDS: one 4B GLDS per thread
  GLDS(props + jbase + tid, sprops + w * 256, 4);

  // stage one 32-row A-tile: ONE 16B GLDS per thread; LDS linear,
  // source pre-swizzled (LDS chunk s of row r holds global chunk s ^ (r&7))
  auto stageA = [&](char* base, int tile) {
    const int jrow0 = jbase + tile * TILE_J;
    const int row   = w * 4 + (lane >> 4);             // 32 rows over 8 waves
    const int colb  = ((lane & 15) << 4) ^ ((row & 7) << 4);
    GLDS(ebf + (size_t)(jrow0 + row) * DIM + (colb >> 1), base + w * 1024, 16);
  };

  v2f es2 = {0.f, 0.f}, ms2 = {0.f, 0.f}, ct2 = {0.f, 0.f};
  const int rswz = (r31 & 7) << 4;     // read-side XOR swizzle
  const v2f c1v = {C1, C1}, mc1v = {-C1, -C1}, pc2 = {pc, pc};

  // compute one staged 32x32-j tile (tile index tt, LDS buffer base)
  auto compute = [&](const char* base, int tt) {
    const int jrow0 = jbase + tt * TILE_J;
    v8s af[8];
#pragma unroll
    for (int kk = 0; kk < 8; ++kk)
      af[kk] = *reinterpret_cast<const v8s*>(
          base + r31 * 256 + ((kk * 32 + hi * 16) ^ rswz));

    v16f acc = {0.f, 0.f, 0.f, 0.f, 0.f, 0.f, 0.f, 0.f,
                0.f, 0.f, 0.f, 0.f, 0.f, 0.f, 0.f, 0.f};
#pragma unroll
    for (int kk = 0; kk < 8; ++kk)
      acc = __builtin_amdgcn_mfma_f32_32x32x16_bf16(af[kk], bfr[kk], acc, 0, 0, 0);

    if ((unsigned)(jrow0 - i0) < (unsigned)BI) {   // tile may contain the diagonal
#pragma unroll
      for (int r = 0; r < 8; ++r) {
        const int row0 = ((2 * r) & 3) + 8 * (r >> 1) + 4 * hi;  // rows row0, row0+1
        const v2f pj2  = *reinterpret_cast<const v2f*>(
            sprops + ((size_t)tt * 32 + row0) * 4);              // broadcast read
        const v2f dot2 = {acc[2 * r], acc[2 * r + 1]};
        const v2f arg  = __builtin_elementwise_fma(dot2, c1v, mc1v);
        const float ex0 = __builtin_amdgcn_exp2f(arg.x);
        const float ex1 = __builtin_amdgcn_exp2f(arg.y);
        const int jr0 = jrow0 + row0;
        const bool neq0 = (jr0 != icol), neq1 = (jr0 + 1 != icol);
        const v2f exv = {neq0 ? ex0 : 0.f, neq1 ? ex1 : 0.f};
        es2 += exv;
        const v2f d = pc2 - pj2, dsq = d * d;
        const v2f msk = {(neq0 && dsq.x < T2) ? 1.f : 0.f,
                         (neq1 && dsq.y < T2) ? 1.f : 0.f};
        ct2 += msk;
        ms2 = __builtin_elementwise_fma(msk, dot2, ms2);
      }
    } else {
#pragma unroll
      for (int r = 0; r < 8; ++r) {
        const int row0 = ((2 * r) & 3) + 8 * (r >> 1) + 4 * hi;
        const v2f pj2  = *reinterpret_cast<const v2f*>(
            sprops + ((size_t)tt * 32 + row0) * 4);
        const v2f dot2 = {acc[2 * r], acc[2 * r + 1]};
        const v2f arg  = __builtin_elementwise_fma(dot2, c1v, mc1v);
        const v2f exv  = {__builtin_amdgcn_exp2f(arg.x), __builtin_amdgcn_exp2f(arg.y)};
        es2 += exv;
        const v2f d = pc2 - pj2, dsq = d * d;
        const v2f msk = {(dsq.x < T2) ? 1.f : 0.f, (dsq.y < T2) ? 1.f : 0.f};
        ct2 += msk;
        ms2 = __builtin_elementwise_fma(msk, dot2, ms2);
      }
    }
  };

  const int phase = (blockIdx.x * 5) & (NT - 1);       // convoy breaker
  stageA(sA + 0 * TB, phase);
  stageA(sA + 1 * TB, (phase + 1) & (NT - 1));
  __syncthreads();                     // tiles staged + props ready

  for (int t = 0; t < NT; t += 2) {
    const int tt0 = (t + phase) & (NT - 1);
    const int tt1 = (t + 1 + phase) & (NT - 1);
    if (t + 2 < NT) {
      stageA(sA + ((t + 2) & 3) * TB, (tt0 + 2) & (NT - 1));
      stageA(sA + ((t + 3) & 3) * TB, (tt1 + 2) & (NT - 1));
    }
    compute(sA + (t & 3) * TB, tt0);
    compute(sA + ((t + 1) & 3) * TB, tt1);
    __syncthreads();   // reads of t,t+1 done; stages for t+2,t+3 landed
  }

  // combine pair-halves, then sum the two hi-halves (lanes l and l+32 hold
  // complementary j-row subsets for the same icol)
  float es = es2.x + es2.y, ms = ms2.x + ms2.y, ct = ct2.x + ct2.y;
  es += __shfl_xor(es, 32);
  ms += __shfl_xor(ms, 32);
  ct += __shfl_xor(ct, 32);

  if (hi == 0) {
    float* p0 = part + (size_t)blockIdx.y * 3 * N_ROWS;  // slot = j-split; i disjoint per bx
    p0[icol]              = es;
    p0[N_ROWS + icol]     = ms;
    p0[2 * N_ROWS + icol] = ct;
  }
}

// ---------------- kernel 3: per-row finalize + partials + last-block final ----------------
// 128 blocks x 64 threads. Each block writes its partial; the LAST block
// (device-scope ticket) re-reads all partials and writes the scalar loss.
// knorm re-inits cnt each call -> deterministic across graph replays.
__global__ __launch_bounds__(64) void kreduce(const float* __restrict__ part,
                                              volatile float* __restrict__ bs,
                                              volatile float* __restrict__ bc,
                                              int* __restrict__ cnt,
                                              float* __restrict__ out) {
  const int row = blockIdx.x * 64 + threadIdx.x;
  float es = 0.f, ms = 0.f, ct = 0.f;
#pragma unroll
  for (int sp = 0; sp < NSLOT; ++sp) {
    const float* p0 = part + (size_t)sp * 3 * N_ROWS;
    es += p0[row];
    ms += p0[N_ROWS + row];
    ct += p0[2 * N_ROWS + row];
  }
  const float lse = 10.0f + logf(es);                       // logsumexp, M=10
  const float per = (ct * lse - 10.0f * ms) / fmaxf(ct, 1.0f);
  float val = (ct > 0.f) ? per : 0.f;
  float vld = (ct > 0.f) ? 1.f : 0.f;
#pragma unroll
  for (int off = 32; off > 0; off >>= 1) {
    val += __shfl_xor(val, off);
    vld += __shfl_xor(vld, off);
  }

  __shared__ int ticket;
  if (threadIdx.x == 0) {
    bs[blockIdx.x] = val;
    bc[blockIdx.x] = vld;
    __threadfence();                       // publish partials (device scope)
    ticket = atomicAdd(cnt, 1);            // device-scope ordering point
  }
  __syncthreads();
  if (ticket == NRB - 1) {                 // last block finalizes
    __threadfence();                       // acquire: see others' partials
    const int l = threadIdx.x;
    float s = bs[l] + bs[l + 64];
    float c = bc[l] + bc[l + 64];
#pragma unroll
    for (int off = 32; off > 0; off >>= 1) {
      s += __shfl_xor(s, off);
      c += __shfl_xor(c, off);
    }
    if (l == 0) out[0] = (c > 0.f) ? (s / c) : 0.f;
  }
}

extern "C" void kernel_launch(void* const* d_in, const int* in_sizes, int n_in,
                              void* d_out, int out_size, void* d_ws, size_t ws_size,
                              hipStream_t stream) {
  const float* emb   = (const float*)d_in[0];
  const float* props = (const float*)d_in[1];
  float* out = (float*)d_out;

  // ws layout: [0, 2MB) bf16 normalized embeddings; then NSLOT*3*N f32 partials;
  // then 128+128 f32 block partials; then ticket counter
  unsigned short* ebf = (unsigned short*)d_ws;
  const size_t EBF_BYTES  = (size_t)N_ROWS * DIM * 2;
  const size_t PART_BYTES = (size_t)NSLOT * 3 * N_ROWS * 4;
  float* part = (float*)((char*)d_ws + EBF_BYTES);
  float* bs   = (float*)((char*)d_ws + EBF_BYTES + PART_BYTES);
  float* bc   = bs + NRB;
  int*   cnt  = (int*)(bc + NRB);

  knorm<<<N_ROWS / 4, 256, 0, stream>>>(emb, ebf, cnt);
  kmain<<<dim3(N_ROWS / BI, NS), 512, 0, stream>>>(ebf, props, part);
  kreduce<<<NRB, 64, 0, stream>>>(part, bs, bc, cnt, out);
}